// Round 1
// baseline (102.579 us; speedup 1.0000x reference)
//
#include <hip/hip_runtime.h>
#include <math.h>

#define D 128
#define N 256
#define B 4

// ---------- helpers ----------

__device__ __forceinline__ float artanhf_clip(float z) {
  z = fminf(fmaxf(z, -1.f + 1e-7f), 1.f - 1e-7f);
  return 0.5f * logf((1.f + z) / (1.f - z));
}

__device__ __forceinline__ float siluf(float v) {
  return v / (1.f + expf(-v));
}

// Full-block sum, result broadcast to all threads. red[] must have blockDim/64 slots.
__device__ __forceinline__ float block_reduce_sum(float v, float* red) {
  const int lane = threadIdx.x & 63;
  const int wid  = threadIdx.x >> 6;
  const int nw   = blockDim.x >> 6;
  #pragma unroll
  for (int off = 32; off; off >>= 1) v += __shfl_xor(v, off, 64);
  __syncthreads();                 // protect red[] from previous use
  if (lane == 0) red[wid] = v;
  __syncthreads();
  float s = red[0];
  for (int w = 1; w < nw; ++w) s += red[w];
  return s;
}

// ---------- kernel 0: weight transposes ----------
// WT[m][k]   = W[k][m]                 (for mx = W @ x)
// W1bT[m][k] = att_w1[k][128+m]        (x_loc half of DenseAtt first layer)
// M1bT[m][k] = mlp_w1[k][128+m]        (support half of node MLP first layer)
// M2T[m][k]  = mlp_w2[k][m]
__global__ void k_prep(const float* __restrict__ W, const float* __restrict__ aw1,
                       const float* __restrict__ mw1, const float* __restrict__ mw2,
                       float* __restrict__ WT, float* __restrict__ W1bT,
                       float* __restrict__ M1bT, float* __restrict__ M2T) {
  const int r = blockIdx.x;   // source row k (output index)
  const int c = threadIdx.x;  // source col m (input index)
  switch (blockIdx.y) {
    case 0: WT[c * D + r]   = W[r * D + c];             break;
    case 1: W1bT[c * D + r] = aw1[r * (2 * D) + D + c]; break;
    case 2: M1bT[c * D + r] = mw1[r * (2 * D) + D + c]; break;
    case 3: M2T[c * D + r]  = mw2[r * D + c];           break;
  }
}

// ---------- kernel 1: hyp_bias = proj(expmap0(b_lin)) ----------
__global__ void k_bias(const float* __restrict__ b_lin, float* __restrict__ hb) {
  __shared__ float red[2];
  const int k = threadIdx.x;
  float u = b_lin[k];
  float un2 = block_reduce_sum(u * u, red);
  float un = fmaxf(sqrtf(un2), 1e-15f);
  float e = tanhf(un) * u / un;
  float en2 = block_reduce_sum(e * e, red);
  float en = fmaxf(sqrtf(en2), 1e-15f);
  if (en > 0.996f) e = e / en * 0.996f;
  hb[k] = e;
}

// ---------- kernel 2: per-node HypLinear + norms + u (transposed) ----------
__global__ __launch_bounds__(128) void k_node(
    const float* __restrict__ x, const float* __restrict__ WT,
    const float* __restrict__ W1bT, const float* __restrict__ hbv,
    float* __restrict__ h, float* __restrict__ nh2, float* __restrict__ uT) {
  const int node = blockIdx.x;  // b*N + i
  const int k = threadIdx.x;
  __shared__ float vl[D];
  __shared__ float red[2];

  float xv = x[node * D + k];
  vl[k] = xv;
  float xn2 = block_reduce_sum(xv * xv, red);  // syncs make vl visible

  // mx = W @ x
  float mx = 0.f;
  #pragma unroll 4
  for (int m = 0; m < D; ++m) mx = fmaf(vl[m], WT[m * D + k], mx);
  float mxn2 = block_reduce_sum(mx * mx, red);

  // mobius_matvec scaling (sc = 1); mx==0 row -> res==0 automatically
  float xn  = fmaxf(sqrtf(xn2), 1e-15f);
  float mxn = fmaxf(sqrtf(mxn2), 1e-15f);
  float r = tanhf(mxn / xn * artanhf_clip(xn));
  float res = r * mx / mxn;

  // proj
  float rn2 = block_reduce_sum(res * res, red);
  float rn = fmaxf(sqrtf(rn2), 1e-15f);
  if (rn > 0.996f) res = res / rn * 0.996f;

  // mobius_add(res, hyp_bias), then proj
  float hbk = hbv[k];
  float x2 = block_reduce_sum(res * res, red);
  float y2 = block_reduce_sum(hbk * hbk, red);
  float xy = block_reduce_sum(res * hbk, red);
  float num = (1.f + 2.f * xy + y2) * res + (1.f - x2) * hbk;
  float den = fmaxf(1.f + 2.f * xy + x2 * y2, 1e-15f);
  float hv = num / den;
  float hn2 = block_reduce_sum(hv * hv, red);
  float hn = fmaxf(sqrtf(hn2), 1e-15f);
  if (hn > 0.996f) hv = hv / hn * 0.996f;

  h[node * D + k] = hv;
  float h2 = block_reduce_sum(hv * hv, red);
  if (k == 0) nh2[node] = h2;

  // u = att_w1[:, D:2D] @ h, stored transposed: uT[b][k][i]
  __syncthreads();
  vl[k] = hv;
  __syncthreads();
  float u = 0.f;
  #pragma unroll 4
  for (int m = 0; m < D; ++m) u = fmaf(vl[m], W1bT[m * D + k], u);
  const int b = node >> 8, i = node & (N - 1);
  uT[(b * D + k) * N + i] = u;
}

// ---------- kernel 3: pairwise attention ----------
// block = (b, i); thread t = j. Emits P[b,i,j] = w*B and accA[b,i] = sum_j w*A,
// where x_loc(i,j) = A*h_i + B*h_j and w = sigmoid(att MLP)*mask.
__global__ __launch_bounds__(256) void k_att(
    const float* __restrict__ h, const float* __restrict__ nh2,
    const float* __restrict__ uT, const float* __restrict__ mask,
    const float* __restrict__ ab1, const float* __restrict__ aw2,
    const float* __restrict__ ab2,
    float* __restrict__ P, float* __restrict__ accA) {
  const int node = blockIdx.x;
  const int b = node >> 8, i = node & (N - 1);
  const int t = threadIdx.x;  // j
  __shared__ float hi[D], ui[D], w2l[D], b1l[D];
  __shared__ float red[4];

  if (t < D) {
    hi[t]  = h[node * D + t];
    ui[t]  = uT[(b * D + t) * N + i];
    w2l[t] = aw2[t];
    b1l[t] = ab1[t];
  }
  __syncthreads();

  // G_ij = h_i . h_j  (thread streams its own h_j row, L2-resident)
  const float4* hj4 = (const float4*)(h + (b * N + t) * D);
  float g = 0.f;
  #pragma unroll 8
  for (int k4 = 0; k4 < D / 4; ++k4) {
    float4 v = hj4[k4];
    g = fmaf(hi[4 * k4 + 0], v.x, g);
    g = fmaf(hi[4 * k4 + 1], v.y, g);
    g = fmaf(hi[4 * k4 + 2], v.z, g);
    g = fmaf(hi[4 * k4 + 3], v.w, g);
  }

  const float n2i = nh2[node];
  const float n2j = nh2[b * N + t];

  // mobius_add(-h_i, h_j) = A0*h_i + B0*h_j
  float alpha = 1.f - 2.f * g + n2j;
  float beta  = 1.f - n2i;
  float den = fmaxf(1.f - 2.f * g + n2i * n2j, 1e-15f);
  float A0 = -alpha / den, B0 = beta / den;
  // ||sub||^2 in closed form (clamp: diagonal cancels catastrophically)
  float sn2 = fmaxf(A0 * A0 * n2i + 2.f * A0 * B0 * g + B0 * B0 * n2j, 0.f);
  float sn = fmaxf(sqrtf(sn2), 1e-15f);
  float coef = fmaxf(1.f - n2i, 1e-15f) * artanhf_clip(sn) / sn;
  float A = coef * A0, Bc = coef * B0;

  // att = sigmoid( w2 . silu(A*u_i + B*u_j + b1) + b2 )
  const float* uTb = uT + b * D * N + t;
  float acc = 0.f;
  #pragma unroll 8
  for (int k = 0; k < D; ++k) {
    float pre = fmaf(A, ui[k], fmaf(Bc, uTb[k * N], b1l[k]));
    acc = fmaf(siluf(pre), w2l[k], acc);
  }
  float att = 1.f / (1.f + expf(-(acc + ab2[0])));
  float w = att * mask[(b * N + i) * N + t];

  P[(b * N + i) * N + t] = w * Bc;
  float wa = block_reduce_sum(w * A, red);
  if (t == 0) accA[node] = wa;
}

// ---------- kernel 4: support GEMM + node MLP + expmap + HypAct ----------
__global__ __launch_bounds__(128) void k_out(
    const float* __restrict__ h, const float* __restrict__ P,
    const float* __restrict__ accA,
    const float* __restrict__ M1bT, const float* __restrict__ M2T,
    const float* __restrict__ mb1, const float* __restrict__ mb2,
    float* __restrict__ out) {
  const int node = blockIdx.x;
  const int b = node >> 8;
  const int k = threadIdx.x;
  __shared__ float sl[D], gl[D];
  __shared__ float red[2];

  const float hk = h[node * D + k];

  // support_t = accA*h_i + sum_j P_ij * h_j
  float s = accA[node] * hk;
  const float* Hb = h + b * N * D;
  const float* Pi = P + node * N;
  #pragma unroll 4
  for (int j = 0; j < N; ++j) s = fmaf(Pi[j], Hb[j * D + k], s);

  // node MLP: silu(t @ mlp_w1.T + b1) @ mlp_w2.T + b2   (x_self half ~ 0)
  sl[k] = s;
  __syncthreads();
  float a = mb1[k];
  #pragma unroll 4
  for (int m = 0; m < D; ++m) a = fmaf(sl[m], M1bT[m * D + k], a);
  float gk = siluf(a);
  gl[k] = gk;
  __syncthreads();
  float s2 = mb2[k];
  #pragma unroll 4
  for (int m = 0; m < D; ++m) s2 = fmaf(gl[m], M2T[m * D + k], s2);

  // expmap(s2, h): second = tanh(0.5*lam*un)*s2/un ; mobius_add(h, second); proj
  float n2p = block_reduce_sum(hk * hk, red);
  float un2 = block_reduce_sum(s2 * s2, red);
  float un = fmaxf(sqrtf(un2), 1e-15f);
  float lam = 2.f / fmaxf(1.f - n2p, 1e-15f);
  float second = tanhf(0.5f * lam * un) * s2 / un;

  float y2 = block_reduce_sum(second * second, red);
  float xy = block_reduce_sum(hk * second, red);
  float num = (1.f + 2.f * xy + y2) * hk + (1.f - n2p) * second;
  float den = fmaxf(1.f + 2.f * xy + n2p * y2, 1e-15f);
  float o = num / den;

  float on2 = block_reduce_sum(o * o, red);
  float on = fmaxf(sqrtf(on2), 1e-15f);
  if (on > 0.996f) o = o / on * 0.996f;

  // HypAct: xt = silu(logmap0(o)); out = proj(expmap0(xt))
  float pn2 = block_reduce_sum(o * o, red);
  float pn = fmaxf(sqrtf(pn2), 1e-15f);
  float xt = artanhf_clip(pn) * o / pn;
  xt = siluf(xt);
  float xn2 = block_reduce_sum(xt * xt, red);
  float xn = fmaxf(sqrtf(xn2), 1e-15f);
  float o2 = tanhf(xn) * xt / xn;
  float o2n2 = block_reduce_sum(o2 * o2, red);
  float o2n = fmaxf(sqrtf(o2n2), 1e-15f);
  if (o2n > 0.996f) o2 = o2 / o2n * 0.996f;

  out[node * D + k] = o2;
}

// ---------- launch ----------
extern "C" void kernel_launch(void* const* d_in, const int* in_sizes, int n_in,
                              void* d_out, int out_size, void* d_ws, size_t ws_size,
                              hipStream_t stream) {
  const float* x     = (const float*)d_in[0];
  const float* mask  = (const float*)d_in[1];
  const float* W     = (const float*)d_in[2];
  const float* b_lin = (const float*)d_in[3];
  const float* aw1   = (const float*)d_in[4];
  const float* ab1   = (const float*)d_in[5];
  const float* aw2   = (const float*)d_in[6];
  const float* ab2   = (const float*)d_in[7];
  const float* mw1   = (const float*)d_in[8];
  const float* mb1   = (const float*)d_in[9];
  const float* mw2   = (const float*)d_in[10];
  const float* mb2   = (const float*)d_in[11];
  float* out = (float*)d_out;

  float* ws   = (float*)d_ws;
  float* h    = ws;              // B*N*D   = 131072
  float* nh2  = h + B * N * D;   // B*N     = 1024
  float* uT   = nh2 + B * N;     // B*D*N   = 131072
  float* P    = uT + B * D * N;  // B*N*N   = 262144
  float* accA = P + B * N * N;   // B*N     = 1024
  float* WT   = accA + B * N;    // D*D
  float* W1bT = WT + D * D;      // D*D
  float* M1bT = W1bT + D * D;    // D*D
  float* M2T  = M1bT + D * D;    // D*D
  float* hb   = M2T + D * D;     // D

  hipLaunchKernelGGL(k_prep, dim3(D, 4), dim3(D), 0, stream,
                     W, aw1, mw1, mw2, WT, W1bT, M1bT, M2T);
  hipLaunchKernelGGL(k_bias, dim3(1), dim3(D), 0, stream, b_lin, hb);
  hipLaunchKernelGGL(k_node, dim3(B * N), dim3(D), 0, stream,
                     x, WT, W1bT, hb, h, nh2, uT);
  hipLaunchKernelGGL(k_att, dim3(B * N), dim3(N), 0, stream,
                     h, nh2, uT, mask, ab1, aw2, ab2, P, accA);
  hipLaunchKernelGGL(k_out, dim3(B * N), dim3(D), 0, stream,
                     h, P, accA, M1bT, M2T, mb1, mb2, out);
}

// Round 2
// 69.602 us; speedup vs baseline: 1.4738x; 1.4738x over previous
//
#include <hip/hip_runtime.h>
#include <math.h>

#define D 128
#define N 256
#define B 4

// ---------- fast native-math helpers (v_exp_f32 / v_log_f32 / v_rcp_f32) ----------

#define LOG2E 1.44269504f
#define LN2   0.69314718f

__device__ __forceinline__ float frcp(float x)  { return __builtin_amdgcn_rcpf(x); }
__device__ __forceinline__ float fexp(float x)  { return __builtin_amdgcn_exp2f(x * LOG2E); }

__device__ __forceinline__ float fsilu(float v) { return v * frcp(1.f + fexp(-v)); }
__device__ __forceinline__ float fsigm(float v) { return frcp(1.f + fexp(-v)); }

// artanh(clip(z)) = 0.5*ln((1+z)/(1-z))
__device__ __forceinline__ float fartanh(float z) {
  z = fminf(fmaxf(z, -1.f + 1e-7f), 1.f - 1e-7f);
  return 0.5f * LN2 * __builtin_amdgcn_logf((1.f + z) * frcp(1.f - z));
}

// tanh for x >= 0 (all our args are norms)
__device__ __forceinline__ float ftanh(float x) {
  float t = __builtin_amdgcn_exp2f(2.f * LOG2E * x);
  return (t - 1.f) * frcp(t + 1.f);
}

// Full-block sum, result broadcast to all threads. red[] must have blockDim/64 slots.
__device__ __forceinline__ float block_reduce_sum(float v, float* red) {
  const int lane = threadIdx.x & 63;
  const int wid  = threadIdx.x >> 6;
  const int nw   = blockDim.x >> 6;
  #pragma unroll
  for (int off = 32; off; off >>= 1) v += __shfl_xor(v, off, 64);
  __syncthreads();                 // protect red[] from previous use
  if (lane == 0) red[wid] = v;
  __syncthreads();
  float s = red[0];
  for (int w = 1; w < nw; ++w) s += red[w];
  return s;
}

// ---------- kernel 0: weight transposes ----------
__global__ void k_prep(const float* __restrict__ W, const float* __restrict__ aw1,
                       const float* __restrict__ mw1, const float* __restrict__ mw2,
                       float* __restrict__ WT, float* __restrict__ W1bT,
                       float* __restrict__ M1bT, float* __restrict__ M2T) {
  const int r = blockIdx.x;   // source row k
  const int c = threadIdx.x;  // source col m
  switch (blockIdx.y) {
    case 0: WT[c * D + r]   = W[r * D + c];             break;
    case 1: W1bT[c * D + r] = aw1[r * (2 * D) + D + c]; break;
    case 2: M1bT[c * D + r] = mw1[r * (2 * D) + D + c]; break;
    case 3: M2T[c * D + r]  = mw2[r * D + c];           break;
  }
}

// ---------- kernel 1: hyp_bias = proj(expmap0(b_lin)) ----------
__global__ void k_bias(const float* __restrict__ b_lin, float* __restrict__ hb) {
  __shared__ float red[2];
  const int k = threadIdx.x;
  float u = b_lin[k];
  float un2 = block_reduce_sum(u * u, red);
  float un = fmaxf(sqrtf(un2), 1e-15f);
  float e = tanhf(un) * u / un;   // cold kernel: keep precise
  float en2 = block_reduce_sum(e * e, red);
  float en = fmaxf(sqrtf(en2), 1e-15f);
  if (en > 0.996f) e = e / en * 0.996f;
  hb[k] = e;
}

// ---------- kernel 2: per-node HypLinear + norms + u (transposed) ----------
__global__ __launch_bounds__(128) void k_node(
    const float* __restrict__ x, const float* __restrict__ WT,
    const float* __restrict__ W1bT, const float* __restrict__ hbv,
    float* __restrict__ h, float* __restrict__ nh2, float* __restrict__ uT) {
  const int node = blockIdx.x;  // b*N + i
  const int k = threadIdx.x;
  __shared__ float vl[D];
  __shared__ float red[2];

  float xv = x[node * D + k];
  vl[k] = xv;
  float xn2 = block_reduce_sum(xv * xv, red);  // syncs make vl visible

  // mx = W @ x  (2-way split accumulator for ILP)
  float mxa = 0.f, mxb = 0.f;
  #pragma unroll 4
  for (int m = 0; m < D; m += 2) {
    mxa = fmaf(vl[m],     WT[m * D + k],       mxa);
    mxb = fmaf(vl[m + 1], WT[(m + 1) * D + k], mxb);
  }
  float mx = mxa + mxb;
  float mxn2 = block_reduce_sum(mx * mx, red);

  float xn  = fmaxf(sqrtf(xn2), 1e-15f);
  float mxn = fmaxf(sqrtf(mxn2), 1e-15f);
  float r = ftanh(mxn * frcp(xn) * fartanh(xn));
  float res = r * mx * frcp(mxn);

  // proj
  float rn2 = block_reduce_sum(res * res, red);
  float rn = fmaxf(sqrtf(rn2), 1e-15f);
  if (rn > 0.996f) res = res * frcp(rn) * 0.996f;

  // mobius_add(res, hyp_bias), then proj
  float hbk = hbv[k];
  float x2 = block_reduce_sum(res * res, red);
  float y2 = block_reduce_sum(hbk * hbk, red);
  float xy = block_reduce_sum(res * hbk, red);
  float num = (1.f + 2.f * xy + y2) * res + (1.f - x2) * hbk;
  float den = fmaxf(1.f + 2.f * xy + x2 * y2, 1e-15f);
  float hv = num * frcp(den);
  float hn2 = block_reduce_sum(hv * hv, red);
  float hn = fmaxf(sqrtf(hn2), 1e-15f);
  if (hn > 0.996f) hv = hv * frcp(hn) * 0.996f;

  h[node * D + k] = hv;
  float h2 = block_reduce_sum(hv * hv, red);
  if (k == 0) nh2[node] = h2;

  // u = att_w1[:, D:2D] @ h, stored transposed: uT[b][k][i]
  __syncthreads();
  vl[k] = hv;
  __syncthreads();
  float ua = 0.f, ub = 0.f;
  #pragma unroll 4
  for (int m = 0; m < D; m += 2) {
    ua = fmaf(vl[m],     W1bT[m * D + k],       ua);
    ub = fmaf(vl[m + 1], W1bT[(m + 1) * D + k], ub);
  }
  const int b = node >> 8, i = node & (N - 1);
  uT[(b * D + k) * N + i] = ua + ub;
}

// ---------- kernel 3: pairwise attention ----------
__global__ __launch_bounds__(256) void k_att(
    const float* __restrict__ h, const float* __restrict__ nh2,
    const float* __restrict__ uT, const float* __restrict__ mask,
    const float* __restrict__ ab1, const float* __restrict__ aw2,
    const float* __restrict__ ab2,
    float* __restrict__ P, float* __restrict__ accA) {
  const int node = blockIdx.x;
  const int b = node >> 8, i = node & (N - 1);
  const int t = threadIdx.x;  // j
  __shared__ float hi[D], ui[D], w2l[D], b1l[D];
  __shared__ float red[4];

  if (t < D) {
    hi[t]  = h[node * D + t];
    ui[t]  = uT[(b * D + t) * N + i];
    w2l[t] = aw2[t];
    b1l[t] = ab1[t];
  }
  const float mk = mask[(b * N + i) * N + t];
  __syncthreads();

  // G_ij = h_i . h_j
  const float4* hj4 = (const float4*)(h + (b * N + t) * D);
  float g0 = 0.f, g1 = 0.f;
  #pragma unroll 8
  for (int k4 = 0; k4 < D / 4; ++k4) {
    float4 v = hj4[k4];
    g0 = fmaf(hi[4 * k4 + 0], v.x, g0);
    g1 = fmaf(hi[4 * k4 + 1], v.y, g1);
    g0 = fmaf(hi[4 * k4 + 2], v.z, g0);
    g1 = fmaf(hi[4 * k4 + 3], v.w, g1);
  }
  float g = g0 + g1;

  const float n2i = nh2[node];
  const float n2j = nh2[b * N + t];

  // mobius_add(-h_i, h_j) = A0*h_i + B0*h_j
  float alpha = 1.f - 2.f * g + n2j;
  float beta  = 1.f - n2i;
  float den = fmaxf(1.f - 2.f * g + n2i * n2j, 1e-15f);
  float rden = frcp(den);
  float A0 = -alpha * rden, B0 = beta * rden;
  float sn2 = fmaxf(A0 * A0 * n2i + 2.f * A0 * B0 * g + B0 * B0 * n2j, 0.f);
  float sn = fmaxf(sqrtf(sn2), 1e-15f);
  float coef = fmaxf(1.f - n2i, 1e-15f) * fartanh(sn) * frcp(sn);
  float A = coef * A0, Bc = coef * B0;

  // att = sigmoid( w2 . silu(A*u_i + B*u_j + b1) + b2 )
  const float* uTb = uT + b * D * N + t;
  float acc0 = 0.f, acc1 = 0.f;
  #pragma unroll 4
  for (int k = 0; k < D; k += 2) {
    float pre0 = fmaf(A, ui[k],     fmaf(Bc, uTb[k * N],       b1l[k]));
    float pre1 = fmaf(A, ui[k + 1], fmaf(Bc, uTb[(k + 1) * N], b1l[k + 1]));
    acc0 = fmaf(fsilu(pre0), w2l[k],     acc0);
    acc1 = fmaf(fsilu(pre1), w2l[k + 1], acc1);
  }
  float att = fsigm(acc0 + acc1 + ab2[0]);
  float w = att * mk;

  P[(b * N + i) * N + t] = w * Bc;
  float wa = block_reduce_sum(w * A, red);
  if (t == 0) accA[node] = wa;
}

// ---------- kernel 4: support GEMM + node MLP + expmap + HypAct ----------
__global__ __launch_bounds__(128) void k_out(
    const float* __restrict__ h, const float* __restrict__ P,
    const float* __restrict__ accA,
    const float* __restrict__ M1bT, const float* __restrict__ M2T,
    const float* __restrict__ mb1, const float* __restrict__ mb2,
    float* __restrict__ out) {
  const int node = blockIdx.x;
  const int b = node >> 8;
  const int k = threadIdx.x;
  __shared__ float sl[D], gl[D];
  __shared__ float red[2];

  const float hk = h[node * D + k];

  // support_t = accA*h_i + sum_j P_ij * h_j  (4-way split accumulator)
  const float* Hb = h + b * N * D;
  const float* Pi = P + node * N;
  float s0 = accA[node] * hk, s1 = 0.f, s2a = 0.f, s3 = 0.f;
  #pragma unroll 4
  for (int j = 0; j < N; j += 4) {
    s0  = fmaf(Pi[j],     Hb[j * D + k],       s0);
    s1  = fmaf(Pi[j + 1], Hb[(j + 1) * D + k], s1);
    s2a = fmaf(Pi[j + 2], Hb[(j + 2) * D + k], s2a);
    s3  = fmaf(Pi[j + 3], Hb[(j + 3) * D + k], s3);
  }
  float s = (s0 + s1) + (s2a + s3);

  // node MLP: silu(t @ mlp_w1.T + b1) @ mlp_w2.T + b2   (x_self half ~ 0)
  sl[k] = s;
  __syncthreads();
  float a0 = mb1[k], a1 = 0.f;
  #pragma unroll 4
  for (int m = 0; m < D; m += 2) {
    a0 = fmaf(sl[m],     M1bT[m * D + k],       a0);
    a1 = fmaf(sl[m + 1], M1bT[(m + 1) * D + k], a1);
  }
  float gk = fsilu(a0 + a1);
  gl[k] = gk;
  __syncthreads();
  float c0 = mb2[k], c1 = 0.f;
  #pragma unroll 4
  for (int m = 0; m < D; m += 2) {
    c0 = fmaf(gl[m],     M2T[m * D + k],       c0);
    c1 = fmaf(gl[m + 1], M2T[(m + 1) * D + k], c1);
  }
  float s2 = c0 + c1;

  // expmap(s2, h): second = tanh(0.5*lam*un)*s2/un ; mobius_add(h, second); proj
  float n2p = block_reduce_sum(hk * hk, red);
  float un2 = block_reduce_sum(s2 * s2, red);
  float un = fmaxf(sqrtf(un2), 1e-15f);
  float lam = 2.f * frcp(fmaxf(1.f - n2p, 1e-15f));
  float second = ftanh(0.5f * lam * un) * s2 * frcp(un);

  float y2 = block_reduce_sum(second * second, red);
  float xy = block_reduce_sum(hk * second, red);
  float num = (1.f + 2.f * xy + y2) * hk + (1.f - n2p) * second;
  float den = fmaxf(1.f + 2.f * xy + n2p * y2, 1e-15f);
  float o = num * frcp(den);

  float on2 = block_reduce_sum(o * o, red);
  float on = fmaxf(sqrtf(on2), 1e-15f);
  if (on > 0.996f) o = o * frcp(on) * 0.996f;

  // HypAct: xt = silu(logmap0(o)); out = proj(expmap0(xt))
  float pn2 = block_reduce_sum(o * o, red);
  float pn = fmaxf(sqrtf(pn2), 1e-15f);
  float xt = fartanh(pn) * o * frcp(pn);
  xt = fsilu(xt);
  float xn2 = block_reduce_sum(xt * xt, red);
  float xn = fmaxf(sqrtf(xn2), 1e-15f);
  float o2 = ftanh(xn) * xt * frcp(xn);
  float o2n2 = block_reduce_sum(o2 * o2, red);
  float o2n = fmaxf(sqrtf(o2n2), 1e-15f);
  if (o2n > 0.996f) o2 = o2 * frcp(o2n) * 0.996f;

  out[node * D + k] = o2;
}

// ---------- launch ----------
extern "C" void kernel_launch(void* const* d_in, const int* in_sizes, int n_in,
                              void* d_out, int out_size, void* d_ws, size_t ws_size,
                              hipStream_t stream) {
  const float* x     = (const float*)d_in[0];
  const float* mask  = (const float*)d_in[1];
  const float* W     = (const float*)d_in[2];
  const float* b_lin = (const float*)d_in[3];
  const float* aw1   = (const float*)d_in[4];
  const float* ab1   = (const float*)d_in[5];
  const float* aw2   = (const float*)d_in[6];
  const float* ab2   = (const float*)d_in[7];
  const float* mw1   = (const float*)d_in[8];
  const float* mb1   = (const float*)d_in[9];
  const float* mw2   = (const float*)d_in[10];
  const float* mb2   = (const float*)d_in[11];
  float* out = (float*)d_out;

  float* ws   = (float*)d_ws;
  float* h    = ws;              // B*N*D   = 131072
  float* nh2  = h + B * N * D;   // B*N     = 1024
  float* uT   = nh2 + B * N;     // B*D*N   = 131072
  float* P    = uT + B * D * N;  // B*N*N   = 262144
  float* accA = P + B * N * N;   // B*N     = 1024
  float* WT   = accA + B * N;    // D*D
  float* W1bT = WT + D * D;      // D*D
  float* M1bT = W1bT + D * D;    // D*D
  float* M2T  = M1bT + D * D;    // D*D
  float* hb   = M2T + D * D;     // D

  hipLaunchKernelGGL(k_prep, dim3(D, 4), dim3(D), 0, stream,
                     W, aw1, mw1, mw2, WT, W1bT, M1bT, M2T);
  hipLaunchKernelGGL(k_bias, dim3(1), dim3(D), 0, stream, b_lin, hb);
  hipLaunchKernelGGL(k_node, dim3(B * N), dim3(D), 0, stream,
                     x, WT, W1bT, hb, h, nh2, uT);
  hipLaunchKernelGGL(k_att, dim3(B * N), dim3(N), 0, stream,
                     h, nh2, uT, mask, ab1, aw2, ab2, P, accA);
  hipLaunchKernelGGL(k_out, dim3(B * N), dim3(D), 0, stream,
                     h, P, accA, M1bT, M2T, mb1, mb2, out);
}

// Round 3
// 51.589 us; speedup vs baseline: 1.9884x; 1.3492x over previous
//
#include <hip/hip_runtime.h>
#include <math.h>

#define D 128
#define N 256
#define B 4

// ---------- fast native-math helpers ----------

#define LOG2E 1.44269504f
#define LN2   0.69314718f
#define PROJ_R 0.996f

__device__ __forceinline__ float frcp(float x)  { return __builtin_amdgcn_rcpf(x); }
__device__ __forceinline__ float fexp(float x)  { return __builtin_amdgcn_exp2f(x * LOG2E); }
__device__ __forceinline__ float fsilu(float v) { return v * frcp(1.f + fexp(-v)); }
__device__ __forceinline__ float fsigm(float v) { return frcp(1.f + fexp(-v)); }

__device__ __forceinline__ float fartanh(float z) {
  z = fminf(fmaxf(z, -1.f + 1e-7f), 1.f - 1e-7f);
  return 0.5f * LN2 * __builtin_amdgcn_logf((1.f + z) * frcp(1.f - z));
}

// tanh for x >= 0 (all our args are norms)
__device__ __forceinline__ float ftanh(float x) {
  float t = __builtin_amdgcn_exp2f(2.f * LOG2E * x);
  return (t - 1.f) * frcp(t + 1.f);
}

__device__ __forceinline__ float wave_sum(float v) {
  #pragma unroll
  for (int off = 32; off; off >>= 1) v += __shfl_xor(v, off, 64);
  return v;
}

// ---- per-128-thread-group reductions in a 512-thread block (4 groups x 2 waves) ----
// red must be float[16]; all 512 threads must call (uniform control flow).
__device__ __forceinline__ float group_sum(float v, float* red) {
  v = wave_sum(v);
  const int grp = threadIdx.x >> 7;
  const int wid = (threadIdx.x >> 6) & 1;
  __syncthreads();
  if ((threadIdx.x & 63) == 0) red[grp * 2 + wid] = v;
  __syncthreads();
  return red[grp * 2] + red[grp * 2 + 1];
}

__device__ __forceinline__ float2 group_sum2(float a, float b, float* red) {
  a = wave_sum(a);
  b = wave_sum(b);
  const int grp = threadIdx.x >> 7;
  const int wid = (threadIdx.x >> 6) & 1;
  __syncthreads();
  if ((threadIdx.x & 63) == 0) { red[grp * 4 + wid * 2] = a; red[grp * 4 + wid * 2 + 1] = b; }
  __syncthreads();
  return make_float2(red[grp * 4] + red[grp * 4 + 2], red[grp * 4 + 1] + red[grp * 4 + 3]);
}

// full 256-thread block sum (k_att)
__device__ __forceinline__ float block_sum256(float v, float* red) {
  v = wave_sum(v);
  const int wid = threadIdx.x >> 6;
  __syncthreads();
  if ((threadIdx.x & 63) == 0) red[wid] = v;
  __syncthreads();
  return (red[0] + red[1]) + (red[2] + red[3]);
}

// ---------- kernel 0: weight transposes + hyp_bias ----------
// y<4: transposes.  y==4, x==0: hyp_bias = proj(expmap0(b_lin)) and its norm^2.
__global__ void k_prep(const float* __restrict__ W, const float* __restrict__ aw1,
                       const float* __restrict__ mw1, const float* __restrict__ mw2,
                       const float* __restrict__ b_lin,
                       float* __restrict__ WT, float* __restrict__ W1bT,
                       float* __restrict__ M1bT, float* __restrict__ M2T,
                       float* __restrict__ hb) {
  const int r = blockIdx.x;
  const int c = threadIdx.x;
  switch (blockIdx.y) {
    case 0: WT[c * D + r]   = W[r * D + c];             return;
    case 1: W1bT[c * D + r] = aw1[r * (2 * D) + D + c]; return;
    case 2: M1bT[c * D + r] = mw1[r * (2 * D) + D + c]; return;
    case 3: M2T[c * D + r]  = mw2[r * D + c];           return;
    default: break;
  }
  if (blockIdx.x != 0) return;
  __shared__ float red[2];
  const int k = threadIdx.x;
  const int wid = k >> 6;
  float u = b_lin[k];
  float s = wave_sum(u * u);
  if ((k & 63) == 0) red[wid] = s;
  __syncthreads();
  float un2 = red[0] + red[1];
  float un = fmaxf(sqrtf(un2), 1e-15f);
  float e = tanhf(un) * u / un;
  __syncthreads();
  s = wave_sum(e * e);
  if ((k & 63) == 0) red[wid] = s;
  __syncthreads();
  float en2 = red[0] + red[1];
  float en = fmaxf(sqrtf(en2), 1e-15f);
  float y2 = en2;
  if (en > PROJ_R) { e = e / en * PROJ_R; y2 = PROJ_R * PROJ_R; }
  hb[k] = e;
  if (k == 0) hb[D] = y2;
}

// ---------- kernel 1: per-node HypLinear + norms + transposed h,u ----------
// 512 threads = 4 nodes x 128 dims.
__global__ __launch_bounds__(512) void k_node(
    const float* __restrict__ x, const float* __restrict__ WT,
    const float* __restrict__ W1bT, const float* __restrict__ hbv,
    float* __restrict__ h, float* __restrict__ hT,
    float* __restrict__ nh2, float* __restrict__ uT) {
  const int grp = threadIdx.x >> 7;
  const int k   = threadIdx.x & 127;
  const int node = blockIdx.x * 4 + grp;     // b*N + i
  const int b = node >> 8, i = node & (N - 1);
  __shared__ float vl[4][D];
  __shared__ float red[16];

  float xv = x[node * D + k];
  vl[grp][k] = xv;
  float xn2 = group_sum(xv * xv, red);       // syncs publish vl

  // mx = W @ x
  float mxa = 0.f, mxb = 0.f;
  #pragma unroll 8
  for (int m = 0; m < D; m += 2) {
    mxa = fmaf(vl[grp][m],     WT[m * D + k],       mxa);
    mxb = fmaf(vl[grp][m + 1], WT[(m + 1) * D + k], mxb);
  }
  float mx = mxa + mxb;
  float mxn2 = group_sum(mx * mx, red);

  float xn  = fmaxf(sqrtf(xn2), 1e-15f);
  float mxn = fmaxf(sqrtf(mxn2), 1e-15f);
  float r = ftanh(mxn * frcp(xn) * fartanh(xn));
  float res = r * mx * frcp(mxn);

  // proj + (res . hyp_bias) fused in one pass
  const float hbk = hbv[k];
  float2 rp = group_sum2(res * res, res * hbk, red);
  float rn2 = rp.x, xy = rp.y;
  float rn = fmaxf(sqrtf(rn2), 1e-15f);
  float x2 = rn2;
  if (rn > PROJ_R) { float sc = PROJ_R * frcp(rn); res *= sc; xy *= sc; x2 = PROJ_R * PROJ_R; }

  // mobius_add(res, hyp_bias), then proj
  const float y2 = hbv[D];
  float num = (1.f + 2.f * xy + y2) * res + (1.f - x2) * hbk;
  float den = fmaxf(1.f + 2.f * xy + x2 * y2, 1e-15f);
  float hv = num * frcp(den);
  float hn2 = group_sum(hv * hv, red);
  float hn = fmaxf(sqrtf(hn2), 1e-15f);
  float h2 = hn2;
  if (hn > PROJ_R) { hv = hv * frcp(hn) * PROJ_R; h2 = PROJ_R * PROJ_R; }

  h[node * D + k] = hv;
  hT[(b * D + k) * N + i] = hv;
  if (k == 0) nh2[node] = h2;

  // u = att_w1[:, D:2D] @ h, stored transposed: uT[b][k][i]
  __syncthreads();
  vl[grp][k] = hv;
  __syncthreads();
  float ua = 0.f, ub = 0.f;
  #pragma unroll 8
  for (int m = 0; m < D; m += 2) {
    ua = fmaf(vl[grp][m],     W1bT[m * D + k],       ua);
    ub = fmaf(vl[grp][m + 1], W1bT[(m + 1) * D + k], ub);
  }
  uT[(b * D + k) * N + i] = ua + ub;
}

// ---------- kernel 2: pairwise attention ----------
__global__ __launch_bounds__(256) void k_att(
    const float* __restrict__ h, const float* __restrict__ hT,
    const float* __restrict__ nh2, const float* __restrict__ uT,
    const float* __restrict__ mask,
    const float* __restrict__ ab1, const float* __restrict__ aw2,
    const float* __restrict__ ab2,
    float* __restrict__ P, float* __restrict__ accA) {
  const int node = blockIdx.x;
  const int b = node >> 8, i = node & (N - 1);
  const int t = threadIdx.x;  // j
  __shared__ float hi[D], ui[D], w2l[D], b1l[D];
  __shared__ float red[4];

  if (t < D) {
    hi[t]  = h[node * D + t];
    ui[t]  = uT[(b * D + t) * N + i];
    w2l[t] = aw2[t];
    b1l[t] = ab1[t];
  }
  const float mk = mask[(b * N + i) * N + t];
  const float bias2 = ab2[0];
  __syncthreads();

  // G_ij = h_i . h_j  (coalesced via hT)
  const float* hTb = hT + b * D * N + t;
  float g0 = 0.f, g1 = 0.f;
  #pragma unroll 8
  for (int k = 0; k < D; k += 2) {
    g0 = fmaf(hi[k],     hTb[k * N],       g0);
    g1 = fmaf(hi[k + 1], hTb[(k + 1) * N], g1);
  }
  float g = g0 + g1;

  const float n2i = nh2[node];
  const float n2j = nh2[b * N + t];

  // mobius_add(-h_i, h_j) = A0*h_i + B0*h_j
  float alpha = 1.f - 2.f * g + n2j;
  float beta  = 1.f - n2i;
  float den = fmaxf(1.f - 2.f * g + n2i * n2j, 1e-15f);
  float rden = frcp(den);
  float A0 = -alpha * rden, B0 = beta * rden;
  float sn2 = fmaxf(A0 * A0 * n2i + 2.f * A0 * B0 * g + B0 * B0 * n2j, 0.f);
  float sn = fmaxf(sqrtf(sn2), 1e-15f);
  float coef = fmaxf(1.f - n2i, 1e-15f) * fartanh(sn) * frcp(sn);
  float A = coef * A0, Bc = coef * B0;

  // att = sigmoid( w2 . silu(A*u_i + B*u_j + b1) + b2 )
  const float* uTb = uT + b * D * N + t;
  float acc0 = 0.f, acc1 = 0.f;
  #pragma unroll 8
  for (int k = 0; k < D; k += 2) {
    float pre0 = fmaf(A, ui[k],     fmaf(Bc, uTb[k * N],       b1l[k]));
    float pre1 = fmaf(A, ui[k + 1], fmaf(Bc, uTb[(k + 1) * N], b1l[k + 1]));
    acc0 = fmaf(fsilu(pre0), w2l[k],     acc0);
    acc1 = fmaf(fsilu(pre1), w2l[k + 1], acc1);
  }
  float w = fsigm(acc0 + acc1 + bias2) * mk;

  P[(b * N + i) * N + t] = w * Bc;
  float wa = block_sum256(w * A, red);
  if (t == 0) accA[node] = wa;
}

// ---------- kernel 3: support GEMM + node MLP + expmap + HypAct ----------
// 512 threads = 4 nodes x 128 dims; P rows staged in LDS; analytic norms.
__global__ __launch_bounds__(512) void k_out(
    const float* __restrict__ h, const float* __restrict__ nh2,
    const float* __restrict__ P, const float* __restrict__ accA,
    const float* __restrict__ M1bT, const float* __restrict__ M2T,
    const float* __restrict__ mb1, const float* __restrict__ mb2,
    float* __restrict__ out) {
  const int grp = threadIdx.x >> 7;
  const int k   = threadIdx.x & 127;
  const int node = blockIdx.x * 4 + grp;
  const int b = node >> 8;
  __shared__ float P_lds[4 * N];
  __shared__ float sl[4][D], gl[4][D];
  __shared__ float red[16];

  // stage this block's 4 P-rows
  #pragma unroll
  for (int idx = threadIdx.x; idx < 4 * N; idx += 512)
    P_lds[idx] = P[blockIdx.x * (4 * N) + idx];
  __syncthreads();

  const float hk = h[node * D + k];

  // support_t = accA*h_i + sum_j P_ij * h_j
  const float* Hb = h + b * N * D;
  const float* Pg = P_lds + grp * N;
  float s0 = accA[node] * hk, s1 = 0.f, s2a = 0.f, s3 = 0.f;
  #pragma unroll 4
  for (int j = 0; j < N; j += 4) {
    s0  = fmaf(Pg[j],     Hb[j * D + k],       s0);
    s1  = fmaf(Pg[j + 1], Hb[(j + 1) * D + k], s1);
    s2a = fmaf(Pg[j + 2], Hb[(j + 2) * D + k], s2a);
    s3  = fmaf(Pg[j + 3], Hb[(j + 3) * D + k], s3);
  }
  float s = (s0 + s1) + (s2a + s3);

  // node MLP: silu(t @ mlp_w1.T + b1) @ mlp_w2.T + b2   (x_self half ~ 0)
  sl[grp][k] = s;
  __syncthreads();
  float a0 = mb1[k], a1 = 0.f;
  #pragma unroll 8
  for (int m = 0; m < D; m += 2) {
    a0 = fmaf(sl[grp][m],     M1bT[m * D + k],       a0);
    a1 = fmaf(sl[grp][m + 1], M1bT[(m + 1) * D + k], a1);
  }
  float gk = fsilu(a0 + a1);
  gl[grp][k] = gk;
  __syncthreads();
  float c0 = mb2[k], c1 = 0.f;
  #pragma unroll 8
  for (int m = 0; m < D; m += 2) {
    c0 = fmaf(gl[grp][m],     M2T[m * D + k],       c0);
    c1 = fmaf(gl[grp][m + 1], M2T[(m + 1) * D + k], c1);
  }
  float s2 = c0 + c1;

  // expmap(s2, h): one fused double-reduction; ||second|| analytic
  const float n2p = nh2[node];
  float2 us = group_sum2(s2 * s2, hk * s2, red);  // un2, h.s2
  float un = fmaxf(sqrtf(us.x), 1e-15f);
  float lam = 2.f * frcp(fmaxf(1.f - n2p, 1e-15f));
  float th = ftanh(0.5f * lam * un);
  float ssc = th * frcp(un);
  float second = ssc * s2;
  float y2 = th * th;            // ||second||^2
  float xy = ssc * us.y;         // h . second

  float num = (1.f + 2.f * xy + y2) * hk + (1.f - n2p) * second;
  float den = fmaxf(1.f + 2.f * xy + n2p * y2, 1e-15f);
  float o = num * frcp(den);

  float on2 = group_sum(o * o, red);
  float on = fmaxf(sqrtf(on2), 1e-15f);
  float pn = on;
  if (on > PROJ_R) { o *= PROJ_R * frcp(on); pn = PROJ_R; }

  // HypAct: xt = silu(logmap0(o)); out = proj(expmap0(xt))
  float xt = fartanh(pn) * frcp(pn) * o;
  xt = fsilu(xt);
  float xn2 = group_sum(xt * xt, red);
  float xn = fmaxf(sqrtf(xn2), 1e-15f);
  float tx = ftanh(xn);
  float o2 = tx * frcp(xn) * xt;
  if (tx > PROJ_R) o2 *= PROJ_R * frcp(tx);   // ||o2|| == tx analytically

  out[node * D + k] = o2;
}

// ---------- launch ----------
extern "C" void kernel_launch(void* const* d_in, const int* in_sizes, int n_in,
                              void* d_out, int out_size, void* d_ws, size_t ws_size,
                              hipStream_t stream) {
  const float* x     = (const float*)d_in[0];
  const float* mask  = (const float*)d_in[1];
  const float* W     = (const float*)d_in[2];
  const float* b_lin = (const float*)d_in[3];
  const float* aw1   = (const float*)d_in[4];
  const float* ab1   = (const float*)d_in[5];
  const float* aw2   = (const float*)d_in[6];
  const float* ab2   = (const float*)d_in[7];
  const float* mw1   = (const float*)d_in[8];
  const float* mb1   = (const float*)d_in[9];
  const float* mw2   = (const float*)d_in[10];
  const float* mb2   = (const float*)d_in[11];
  float* out = (float*)d_out;

  float* ws   = (float*)d_ws;
  float* h    = ws;              // B*N*D   = 131072
  float* hT   = h + B * N * D;   // B*D*N   = 131072
  float* nh2  = hT + B * D * N;  // B*N     = 1024
  float* uT   = nh2 + B * N;     // B*D*N   = 131072
  float* P    = uT + B * D * N;  // B*N*N   = 262144
  float* accA = P + B * N * N;   // B*N     = 1024
  float* WT   = accA + B * N;    // D*D
  float* W1bT = WT + D * D;      // D*D
  float* M1bT = W1bT + D * D;    // D*D
  float* M2T  = M1bT + D * D;    // D*D
  float* hb   = M2T + D * D;     // D+1

  hipLaunchKernelGGL(k_prep, dim3(D, 5), dim3(D), 0, stream,
                     W, aw1, mw1, mw2, b_lin, WT, W1bT, M1bT, M2T, hb);
  hipLaunchKernelGGL(k_node, dim3(B * N / 4), dim3(512), 0, stream,
                     x, WT, W1bT, hb, h, hT, nh2, uT);
  hipLaunchKernelGGL(k_att, dim3(B * N), dim3(N), 0, stream,
                     h, hT, nh2, uT, mask, ab1, aw2, ab2, P, accA);
  hipLaunchKernelGGL(k_out, dim3(B * N / 4), dim3(512), 0, stream,
                     h, nh2, P, accA, M1bT, M2T, mb1, mb2, out);
}